// Round 7
// baseline (1838.744 us; speedup 1.0000x reference)
//
#include <hip/hip_runtime.h>
#include <hip/hip_bf16.h>

#define HID 256
#define NCODES 18
#define SCAN_CHUNK 2048
#define LROW 264   // LDS row stride in fp16 (33 chunks of 8) -> conflict-free spread
#define BSH 7      // 128 nodes per CSR bucket

typedef _Float16 h8_t __attribute__((ext_vector_type(8)));
typedef _Float16 h4_t __attribute__((ext_vector_type(4)));
typedef float f4_t __attribute__((ext_vector_type(4)));

// e-table: 18 distinct edge embeddings = ee1[a0] + ee2[a1], fp16
__global__ void etab_kernel(const float* __restrict__ ee1, const float* __restrict__ ee2,
                            _Float16* __restrict__ etab) {
    int t = blockIdx.x;
    int c = threadIdx.x;
    etab[t * HID + c] = (_Float16)(ee1[(t / 3) * HID + c] + ee2[(t % 3) * HID + c]);
}

// zh[n] = fp16(xe1[x[n,0]] + xe2[x[n,1]])
__global__ __launch_bounds__(256) void embed_kernel(const int* __restrict__ x,
                                                    const float* __restrict__ xe1,
                                                    const float* __restrict__ xe2,
                                                    _Float16* __restrict__ zh, int N) {
    int node = blockIdx.x * 4 + (threadIdx.x >> 6);
    int lane = threadIdx.x & 63;
    if (node >= N) return;
    int a0 = x[node * 2 + 0];
    int a1 = x[node * 2 + 1];
    const float4 u = *(const float4*)(xe1 + (size_t)a0 * HID + lane * 4);
    const float4 v = *(const float4*)(xe2 + (size_t)a1 * HID + lane * 4);
    h4_t r;
    r.x = (_Float16)(u.x + v.x); r.y = (_Float16)(u.y + v.y);
    r.z = (_Float16)(u.z + v.z); r.w = (_Float16)(u.w + v.w);
    *(h4_t*)(zh + (size_t)node * HID + lane * 4) = r;
}

// W [5][256][256] fp32 row-major -> Wt fp16 transposed (Wt[n][k]=W[k][n])
__global__ __launch_bounds__(256) void prep_w(const float* __restrict__ W,
                                              _Float16* __restrict__ Wt) {
    __shared__ float t[32][33];
    int m = blockIdx.z;
    int tx = threadIdx.x & 31, ty = threadIdx.x >> 5;
    const float* Wm = W + (size_t)m * HID * HID;
    _Float16* Wtm = Wt + (size_t)m * HID * HID;
    int k0 = blockIdx.x * 32, n0 = blockIdx.y * 32;
#pragma unroll
    for (int j = 0; j < 4; ++j) { int r = ty + j * 8; t[r][tx] = Wm[(k0 + r) * HID + n0 + tx]; }
    __syncthreads();
#pragma unroll
    for (int j = 0; j < 4; ++j) { int r = ty + j * 8; Wtm[(size_t)(n0 + r) * HID + k0 + tx] = (_Float16)t[tx][r]; }
}

__global__ void hist_kernel(const int* __restrict__ ei, int E, int* __restrict__ deg) {
    int i = blockIdx.x * 256 + threadIdx.x;
    if (i < E) atomicAdd(&deg[ei[E + i]], 1);
}

__global__ __launch_bounds__(256) void scan_partial(const int* __restrict__ deg, int n,
                                                    int* __restrict__ psum) {
    __shared__ int red[256];
    int base = blockIdx.x * SCAN_CHUNK;
    int s = 0;
    for (int i = threadIdx.x; i < SCAN_CHUNK; i += 256) {
        int idx = base + i;
        if (idx < n) s += deg[idx];
    }
    red[threadIdx.x] = s;
    __syncthreads();
    for (int off = 128; off > 0; off >>= 1) {
        if (threadIdx.x < off) red[threadIdx.x] += red[threadIdx.x + off];
        __syncthreads();
    }
    if (threadIdx.x == 0) psum[blockIdx.x] = red[0];
}

__global__ void scan_sums(int* psum, int nchunks) {
    if (blockIdx.x == 0 && threadIdx.x == 0) {
        int acc = 0;
        for (int i = 0; i < nchunks; i++) { int v = psum[i]; psum[i] = acc; acc += v; }
    }
}

__global__ __launch_bounds__(256) void scan_apply(const int* __restrict__ deg, int n,
                                                  const int* __restrict__ psum,
                                                  int* __restrict__ row_start,
                                                  int* __restrict__ cursor, int E) {
    __shared__ int tmp[256];
    int tid = threadIdx.x;
    int base = blockIdx.x * SCAN_CHUNK;
    int tb = base + tid * 8;
    int loc[8];
    int s = 0;
    for (int j = 0; j < 8; j++) {
        loc[j] = s;
        int idx = tb + j;
        if (idx < n) s += deg[idx];
    }
    tmp[tid] = s;
    __syncthreads();
    for (int off = 1; off < 256; off <<= 1) {
        int v = 0;
        if (tid >= off) v = tmp[tid - off];
        __syncthreads();
        if (tid >= off) tmp[tid] += v;
        __syncthreads();
    }
    int excl = tmp[tid] - s + psum[blockIdx.x];
    for (int j = 0; j < 8; j++) {
        int idx = tb + j;
        if (idx < n) {
            int v = excl + loc[j];
            row_start[idx] = v;
            cursor[idx] = v;
        }
    }
    if (blockIdx.x == 0 && tid == 0) row_start[n] = E;
}

// bucket cursors: bcur[b] = row_start[b*128]
__global__ void init_bcur(const int* __restrict__ row_start, int* __restrict__ bcur, int nb) {
    int b = blockIdx.x * 256 + threadIdx.x;
    if (b < nb) bcur[b] = row_start[b << BSH];
}

// pass A: scatter edges into dst-buckets (128 nodes/bucket).
// payload: src(17b) | code<<17 (5b) | (dst&127)<<22 (7b)
__global__ void bucket_scatter(const int* __restrict__ ei, const int* __restrict__ ea, int E,
                               int* __restrict__ bcur, unsigned* __restrict__ tmp) {
    int i = blockIdx.x * 256 + threadIdx.x;
    if (i >= E) return;
    int dst = ei[E + i];
    int src = ei[i];
    int code = ea[i * 2] * 3 + ea[i * 2 + 1];
    int b = dst >> BSH;
    int p = atomicAdd(&bcur[b], 1);
    tmp[p] = (unsigned)src | ((unsigned)code << 17) | ((unsigned)(dst & 127) << 22);
}

// pass B: within each bucket, scatter to exact CSR slots (cursor+csr windows stay hot)
__global__ __launch_bounds__(256) void bucket_fill(const int* __restrict__ row_start,
                                                   const unsigned* __restrict__ tmp,
                                                   int* __restrict__ cursor,
                                                   unsigned* __restrict__ csr, int N) {
    int b = blockIdx.x;
    int lo = b << BSH;
    int hi = lo + (1 << BSH);
    if (hi > N) hi = N;
    int base = row_start[lo];
    int cnt = row_start[hi] - base;
    for (int i = threadIdx.x; i < cnt; i += 256) {
        unsigned e = tmp[base + i];
        int dst = lo + ((e >> 22) & 127);
        int pos = atomicAdd(&cursor[dst], 1);
        csr[pos] = (e & 0x1FFFF) | (((e >> 17) & 31) << 20);
    }
}

// h0h[n] = fp16( zh[n] + sum_in relu(zh[src]+etab[code]) )
// 32 nodes/block (2 per wave per pair-iter), etab staged in LDS, packed fp16 math.
__global__ __launch_bounds__(256) void agg_kernel(const _Float16* __restrict__ zh,
                                                  const int* __restrict__ row_start,
                                                  const unsigned* __restrict__ csr,
                                                  const _Float16* __restrict__ etab,
                                                  _Float16* __restrict__ h0h, int N) {
    __shared__ _Float16 et[NCODES * HID];   // 9 KB
    int tid = threadIdx.x;
    // stage etab (18*256 halfs = 576 h8 chunks)
    for (int c = tid; c < NCODES * 32; c += 256)
        *(h8_t*)(et + c * 8) = *(const h8_t*)(etab + c * 8);
    __syncthreads();

    int w = tid >> 6;
    int l32 = tid & 31;
    int half = (tid >> 5) & 1;
    int base = blockIdx.x * 32 + w * 8;
    const h8_t hz = {};

    for (int t = 0; t < 4; ++t) {
        int node = base + t * 2 + half;
        if (node >= N) continue;
        h8_t self = *(const h8_t*)(zh + (size_t)node * HID + l32 * 8);
        float acc[8];
#pragma unroll
        for (int j = 0; j < 8; ++j) acc[j] = (float)self[j];
        int s = row_start[node];
        int e = row_start[node + 1];
        int i = s;
        for (; i + 4 <= e; i += 4) {
            unsigned p0 = csr[i], p1 = csr[i + 1], p2 = csr[i + 2], p3 = csr[i + 3];
            h8_t z0 = *(const h8_t*)(zh + (size_t)(p0 & 0xFFFFF) * HID + l32 * 8);
            h8_t z1 = *(const h8_t*)(zh + (size_t)(p1 & 0xFFFFF) * HID + l32 * 8);
            h8_t z2 = *(const h8_t*)(zh + (size_t)(p2 & 0xFFFFF) * HID + l32 * 8);
            h8_t z3 = *(const h8_t*)(zh + (size_t)(p3 & 0xFFFFF) * HID + l32 * 8);
            h8_t e0 = *(const h8_t*)(et + (p0 >> 20) * HID + l32 * 8);
            h8_t e1 = *(const h8_t*)(et + (p1 >> 20) * HID + l32 * 8);
            h8_t e2 = *(const h8_t*)(et + (p2 >> 20) * HID + l32 * 8);
            h8_t e3 = *(const h8_t*)(et + (p3 >> 20) * HID + l32 * 8);
            h8_t m0 = __builtin_elementwise_max(z0 + e0, hz);
            h8_t m1 = __builtin_elementwise_max(z1 + e1, hz);
            h8_t m2 = __builtin_elementwise_max(z2 + e2, hz);
            h8_t m3 = __builtin_elementwise_max(z3 + e3, hz);
            h8_t sm = (m0 + m1) + (m2 + m3);   // fp16 pairwise partial sum
#pragma unroll
            for (int j = 0; j < 8; ++j) acc[j] += (float)sm[j];
        }
        for (; i < e; ++i) {
            unsigned p0 = csr[i];
            h8_t z0 = *(const h8_t*)(zh + (size_t)(p0 & 0xFFFFF) * HID + l32 * 8);
            h8_t e0 = *(const h8_t*)(et + (p0 >> 20) * HID + l32 * 8);
            h8_t m0 = __builtin_elementwise_max(z0 + e0, hz);
#pragma unroll
            for (int j = 0; j < 8; ++j) acc[j] += (float)m0[j];
        }
        h8_t o;
#pragma unroll
        for (int j = 0; j < 8; ++j) o[j] = (_Float16)acc[j];
        *(h8_t*)(h0h + (size_t)node * HID + l32 * 8) = o;
    }
}

// MLP: z = relu( relu(A@W1+b1) @ W2 + b2 ).  512 thr / 8 waves; BM=64;
// wave w owns rows (w>>2)*32..+32, cols (w&3)*64..+64. 67.6 KB LDS -> 2 blocks/CU.
__global__ __launch_bounds__(512, 4) void mlp_kernel(const _Float16* __restrict__ A,
                                                     const _Float16* __restrict__ Wt1,
                                                     const float* __restrict__ b1,
                                                     const _Float16* __restrict__ Wt2,
                                                     const float* __restrict__ b2,
                                                     _Float16* __restrict__ outh,
                                                     float* __restrict__ outf,
                                                     int M, int writef) {
    __shared__ _Float16 As[64 * LROW];   // ~33.8 KB
    __shared__ _Float16 Ys[64 * LROW];   // ~33.8 KB
    int tid = threadIdx.x;
    int lane = tid & 63;
    int w = tid >> 6;
    int row0 = blockIdx.x * 64;
    const _Float16* Ab = A + (size_t)row0 * HID;

    // stage 64x256 fp16 (2048 chunks / 512 thr = 4 iters)
#pragma unroll
    for (int it = 0; it < 4; ++it) {
        int c = it * 512 + tid;
        int row = c >> 5, cir = c & 31;
        *(h8_t*)(As + row * LROW + cir * 8) = *(const h8_t*)(Ab + row * HID + cir * 8);
    }
    __syncthreads();

    int mh = (w >> 2) * 32;
    int wc = (w & 3) * 64;
    int l16 = lane & 15;
    int lq = lane >> 4;

    // ---- GEMM1: y = relu(A@W1+b1) -> Ys ----
    {
        f4_t acc[2][4] = {};
#pragma unroll
        for (int ks = 0; ks < 8; ++ks) {
            h8_t a[2], b[4];
#pragma unroll
            for (int mi = 0; mi < 2; ++mi)
                a[mi] = *(const h8_t*)(As + (mh + mi * 16 + l16) * LROW + (ks * 4 + lq) * 8);
#pragma unroll
            for (int ni = 0; ni < 4; ++ni)
                b[ni] = *(const h8_t*)(Wt1 + (size_t)(wc + ni * 16 + l16) * HID + ks * 32 + lq * 8);
#pragma unroll
            for (int mi = 0; mi < 2; ++mi)
#pragma unroll
                for (int ni = 0; ni < 4; ++ni)
                    acc[mi][ni] = __builtin_amdgcn_mfma_f32_16x16x32_f16(a[mi], b[ni], acc[mi][ni], 0, 0, 0);
        }
#pragma unroll
        for (int ni = 0; ni < 4; ++ni) {
            int col = wc + ni * 16 + l16;
            float bv = b1[col];
#pragma unroll
            for (int mi = 0; mi < 2; ++mi)
#pragma unroll
                for (int r = 0; r < 4; ++r) {
                    int rr = mh + mi * 16 + lq * 4 + r;
                    Ys[rr * LROW + col] = (_Float16)fmaxf(acc[mi][ni][r] + bv, 0.f);
                }
        }
    }
    __syncthreads();

    // ---- GEMM2: z = relu(y@W2+b2) -> As (reuse) ----
    {
        f4_t acc[2][4] = {};
#pragma unroll
        for (int ks = 0; ks < 8; ++ks) {
            h8_t a[2], b[4];
#pragma unroll
            for (int mi = 0; mi < 2; ++mi)
                a[mi] = *(const h8_t*)(Ys + (mh + mi * 16 + l16) * LROW + (ks * 4 + lq) * 8);
#pragma unroll
            for (int ni = 0; ni < 4; ++ni)
                b[ni] = *(const h8_t*)(Wt2 + (size_t)(wc + ni * 16 + l16) * HID + ks * 32 + lq * 8);
#pragma unroll
            for (int mi = 0; mi < 2; ++mi)
#pragma unroll
                for (int ni = 0; ni < 4; ++ni)
                    acc[mi][ni] = __builtin_amdgcn_mfma_f32_16x16x32_f16(a[mi], b[ni], acc[mi][ni], 0, 0, 0);
        }
        __syncthreads();   // Ys fully consumed before As overwritten? As!=Ys, but As stage must be done being read: GEMM1 read As; all waves past first barrier; safe to overwrite As only after ALL waves finished GEMM1 reads -> this barrier covers it
#pragma unroll
        for (int ni = 0; ni < 4; ++ni) {
            int col = wc + ni * 16 + l16;
            float bv = b2[col];
#pragma unroll
            for (int mi = 0; mi < 2; ++mi)
#pragma unroll
                for (int r = 0; r < 4; ++r) {
                    int rr = mh + mi * 16 + lq * 4 + r;
                    As[rr * LROW + col] = (_Float16)fmaxf(acc[mi][ni][r] + bv, 0.f);
                }
        }
    }
    __syncthreads();

    // ---- coalesced store ----
#pragma unroll
    for (int it = 0; it < 4; ++it) {
        int c = it * 512 + tid;
        int row = c >> 5, cir = c & 31;
        int grow = row0 + row;
        if (grow < M) {
            h8_t v = *(const h8_t*)(As + row * LROW + cir * 8);
            *(h8_t*)(outh + (size_t)grow * HID + cir * 8) = v;
            if (writef) {
                f4_t f0, f1;
#pragma unroll
                for (int j = 0; j < 4; ++j) { f0[j] = (float)v[j]; f1[j] = (float)v[j + 4]; }
                *(f4_t*)(outf + (size_t)grow * HID + cir * 8) = f0;
                *(f4_t*)(outf + (size_t)grow * HID + cir * 8 + 4) = f1;
            }
        }
    }
}

// mean pool from zh: 1024 thr/block, 32 rows in flight x 32 h8 chunks, LDS reduce
__global__ __launch_bounds__(1024) void pool_kernel(const _Float16* __restrict__ zh,
                                                    const int* __restrict__ batch, int N,
                                                    float* __restrict__ g) {
    __shared__ float red[32 * 32 * 8];
    int gid = blockIdx.x;
    int lo = 0, hi = N;
    while (lo < hi) { int mid = (lo + hi) >> 1; if (batch[mid] < gid) lo = mid + 1; else hi = mid; }
    int start = lo;
    int lo2 = start, hi2 = N;
    while (lo2 < hi2) { int mid = (lo2 + hi2) >> 1; if (batch[mid] < gid + 1) lo2 = mid + 1; else hi2 = mid; }
    int end = lo2;
    int cnt = end - start;

    int r = threadIdx.x >> 5;
    int ch = threadIdx.x & 31;
    float acc[8] = {};
    for (int row = start + r; row < end; row += 32) {
        h8_t v = *(const h8_t*)(zh + (size_t)row * HID + ch * 8);
#pragma unroll
        for (int j = 0; j < 8; ++j) acc[j] += (float)v[j];
    }
    float* slot = red + (r * 32 + ch) * 8;
#pragma unroll
    for (int j = 0; j < 8; ++j) slot[j] = acc[j];
    __syncthreads();
    for (int off = 16; off > 0; off >>= 1) {
        if (r < off) {
            const float* o = red + ((r + off) * 32 + ch) * 8;
#pragma unroll
            for (int j = 0; j < 8; ++j) { acc[j] += o[j]; slot[j] = acc[j]; }
        }
        __syncthreads();
    }
    if (r == 0) {
        float inv = 1.0f / fmaxf((float)cnt, 1.0f);
#pragma unroll
        for (int j = 0; j < 8; ++j) g[(size_t)gid * HID + ch * 8 + j] = acc[j] * inv;
    }
}

extern "C" void kernel_launch(void* const* d_in, const int* in_sizes, int n_in,
                              void* d_out, int out_size, void* d_ws, size_t ws_size,
                              hipStream_t stream) {
    const int* x = (const int*)d_in[0];
    const int* ei = (const int*)d_in[1];
    const int* ea = (const int*)d_in[2];
    const int* batch = (const int*)d_in[3];
    const float* xe1 = (const float*)d_in[4];
    const float* xe2 = (const float*)d_in[5];
    const float* ee1 = (const float*)d_in[6];
    const float* ee2 = (const float*)d_in[7];
    const float* W1 = (const float*)d_in[8];
    const float* b1 = (const float*)d_in[9];
    const float* W2 = (const float*)d_in[10];
    const float* b2 = (const float*)d_in[11];

    int N = in_sizes[0] / 2;
    int E = in_sizes[1] / 2;
    int G = out_size / HID - N;
    int nbm = (N + 63) / 64;
    int Np = nbm * 64;
    int nb = (N + (1 << BSH) - 1) >> BSH;

    float* z = (float*)d_out;                       // [N,256] fp32 (final layer)
    float* gout = z + (size_t)N * HID;              // [G,256]

    char* w = (char*)d_ws;
    _Float16* h0h = (_Float16*)w;  w += (size_t)Np * HID * 2;
    _Float16* zh  = (_Float16*)w;  w += (size_t)Np * HID * 2;
    _Float16* Wt1 = (_Float16*)w;  w += (size_t)5 * HID * HID * 2;
    _Float16* Wt2 = (_Float16*)w;  w += (size_t)5 * HID * HID * 2;
    _Float16* etabh = (_Float16*)w; w += (size_t)NCODES * HID * 2;
    int* deg = (int*)w;       w += (size_t)N * 4;
    int* row_start = (int*)w; w += (size_t)(N + 1) * 4;
    int* cursor = (int*)w;    w += (size_t)N * 4;
    int* psum = (int*)w;      w += 64 * 4;
    int* bcur = (int*)w;      w += 1024 * 4;
    unsigned* csr = (unsigned*)w; w += (size_t)E * 4;
    unsigned* tmp = (unsigned*)w;

    hipMemsetAsync(deg, 0, (size_t)N * 4, stream);
    etab_kernel<<<NCODES, HID, 0, stream>>>(ee1, ee2, etabh);
    embed_kernel<<<(N + 3) / 4, 256, 0, stream>>>(x, xe1, xe2, zh, N);
    prep_w<<<dim3(8, 8, 5), 256, 0, stream>>>(W1, Wt1);
    prep_w<<<dim3(8, 8, 5), 256, 0, stream>>>(W2, Wt2);
    hist_kernel<<<(E + 255) / 256, 256, 0, stream>>>(ei, E, deg);
    int nchunks = (N + SCAN_CHUNK - 1) / SCAN_CHUNK;
    scan_partial<<<nchunks, 256, 0, stream>>>(deg, N, psum);
    scan_sums<<<1, 1, 0, stream>>>(psum, nchunks);
    scan_apply<<<nchunks, 256, 0, stream>>>(deg, N, psum, row_start, cursor, E);
    init_bcur<<<(nb + 255) / 256, 256, 0, stream>>>(row_start, bcur, nb);
    bucket_scatter<<<(E + 255) / 256, 256, 0, stream>>>(ei, ea, E, bcur, tmp);
    bucket_fill<<<nb, 256, 0, stream>>>(row_start, tmp, cursor, csr, N);

    for (int l = 0; l < 5; l++) {
        agg_kernel<<<(N + 31) / 32, 256, 0, stream>>>(zh, row_start, csr, etabh, h0h, N);
        mlp_kernel<<<nbm, 512, 0, stream>>>(h0h, Wt1 + (size_t)l * HID * HID,
                                            b1 + (size_t)l * HID,
                                            Wt2 + (size_t)l * HID * HID,
                                            b2 + (size_t)l * HID,
                                            zh, z, N, (l == 4) ? 1 : 0);
    }
    pool_kernel<<<G, 1024, 0, stream>>>(zh, batch, N, gout);
}

// Round 8
// 1513.493 us; speedup vs baseline: 1.2149x; 1.2149x over previous
//
#include <hip/hip_runtime.h>
#include <hip/hip_bf16.h>

#define HID 256
#define NCODES 18
#define SCAN_CHUNK 2048
#define LROW 264   // LDS row stride in fp16 (33 chunks of 8) -> conflict-free spread

typedef _Float16 h8_t __attribute__((ext_vector_type(8)));
typedef _Float16 h4_t __attribute__((ext_vector_type(4)));
typedef float f4_t __attribute__((ext_vector_type(4)));

// e-table: 18 distinct edge embeddings = ee1[a0] + ee2[a1], fp16
__global__ void etab_kernel(const float* __restrict__ ee1, const float* __restrict__ ee2,
                            _Float16* __restrict__ etab) {
    int t = blockIdx.x;
    int c = threadIdx.x;
    etab[t * HID + c] = (_Float16)(ee1[(t / 3) * HID + c] + ee2[(t % 3) * HID + c]);
}

// zh[n] = fp16(xe1[x[n,0]] + xe2[x[n,1]])
__global__ __launch_bounds__(256) void embed_kernel(const int* __restrict__ x,
                                                    const float* __restrict__ xe1,
                                                    const float* __restrict__ xe2,
                                                    _Float16* __restrict__ zh, int N) {
    int node = blockIdx.x * 4 + (threadIdx.x >> 6);
    int lane = threadIdx.x & 63;
    if (node >= N) return;
    int a0 = x[node * 2 + 0];
    int a1 = x[node * 2 + 1];
    const float4 u = *(const float4*)(xe1 + (size_t)a0 * HID + lane * 4);
    const float4 v = *(const float4*)(xe2 + (size_t)a1 * HID + lane * 4);
    h4_t r;
    r.x = (_Float16)(u.x + v.x); r.y = (_Float16)(u.y + v.y);
    r.z = (_Float16)(u.z + v.z); r.w = (_Float16)(u.w + v.w);
    *(h4_t*)(zh + (size_t)node * HID + lane * 4) = r;
}

// W [5][256][256] fp32 row-major -> Wt fp16 transposed (Wt[n][k]=W[k][n])
__global__ __launch_bounds__(256) void prep_w(const float* __restrict__ W,
                                              _Float16* __restrict__ Wt) {
    __shared__ float t[32][33];
    int m = blockIdx.z;
    int tx = threadIdx.x & 31, ty = threadIdx.x >> 5;
    const float* Wm = W + (size_t)m * HID * HID;
    _Float16* Wtm = Wt + (size_t)m * HID * HID;
    int k0 = blockIdx.x * 32, n0 = blockIdx.y * 32;
#pragma unroll
    for (int j = 0; j < 4; ++j) { int r = ty + j * 8; t[r][tx] = Wm[(k0 + r) * HID + n0 + tx]; }
    __syncthreads();
#pragma unroll
    for (int j = 0; j < 4; ++j) { int r = ty + j * 8; Wtm[(size_t)(n0 + r) * HID + k0 + tx] = (_Float16)t[tx][r]; }
}

__global__ void hist_kernel(const int* __restrict__ ei, int E, int* __restrict__ deg) {
    int i = blockIdx.x * 256 + threadIdx.x;
    if (i < E) atomicAdd(&deg[ei[E + i]], 1);
}

__global__ __launch_bounds__(256) void scan_partial(const int* __restrict__ deg, int n,
                                                    int* __restrict__ psum) {
    __shared__ int red[256];
    int base = blockIdx.x * SCAN_CHUNK;
    int s = 0;
    for (int i = threadIdx.x; i < SCAN_CHUNK; i += 256) {
        int idx = base + i;
        if (idx < n) s += deg[idx];
    }
    red[threadIdx.x] = s;
    __syncthreads();
    for (int off = 128; off > 0; off >>= 1) {
        if (threadIdx.x < off) red[threadIdx.x] += red[threadIdx.x + off];
        __syncthreads();
    }
    if (threadIdx.x == 0) psum[blockIdx.x] = red[0];
}

__global__ void scan_sums(int* psum, int nchunks) {
    if (blockIdx.x == 0 && threadIdx.x == 0) {
        int acc = 0;
        for (int i = 0; i < nchunks; i++) { int v = psum[i]; psum[i] = acc; acc += v; }
    }
}

__global__ __launch_bounds__(256) void scan_apply(const int* __restrict__ deg, int n,
                                                  const int* __restrict__ psum,
                                                  int* __restrict__ row_start,
                                                  int* __restrict__ cursor, int E) {
    __shared__ int tmp[256];
    int tid = threadIdx.x;
    int base = blockIdx.x * SCAN_CHUNK;
    int tb = base + tid * 8;
    int loc[8];
    int s = 0;
    for (int j = 0; j < 8; j++) {
        loc[j] = s;
        int idx = tb + j;
        if (idx < n) s += deg[idx];
    }
    tmp[tid] = s;
    __syncthreads();
    for (int off = 1; off < 256; off <<= 1) {
        int v = 0;
        if (tid >= off) v = tmp[tid - off];
        __syncthreads();
        if (tid >= off) tmp[tid] += v;
        __syncthreads();
    }
    int excl = tmp[tid] - s + psum[blockIdx.x];
    for (int j = 0; j < 8; j++) {
        int idx = tb + j;
        if (idx < n) {
            int v = excl + loc[j];
            row_start[idx] = v;
            cursor[idx] = v;
        }
    }
    if (blockIdx.x == 0 && tid == 0) row_start[n] = E;
}

// csr[p] = src | (code << 20), p slot-allocated per dst (low-contention atomics)
__global__ void fill_kernel(const int* __restrict__ ei, const int* __restrict__ ea, int E,
                            int* __restrict__ cursor, unsigned* __restrict__ csr) {
    int i = blockIdx.x * 256 + threadIdx.x;
    if (i >= E) return;
    int dst = ei[E + i];
    int src = ei[i];
    int code = ea[i * 2] * 3 + ea[i * 2 + 1];
    int p = atomicAdd(&cursor[dst], 1);
    csr[p] = (unsigned)src | ((unsigned)code << 20);
}

// h0h[n] = fp16( zh[n] + sum_in relu(zh[src]+etab[code]) )
// 32 nodes/block (2 per wave per pair-iter), etab staged in LDS, packed fp16 math.
__global__ __launch_bounds__(256) void agg_kernel(const _Float16* __restrict__ zh,
                                                  const int* __restrict__ row_start,
                                                  const unsigned* __restrict__ csr,
                                                  const _Float16* __restrict__ etab,
                                                  _Float16* __restrict__ h0h, int N) {
    __shared__ _Float16 et[NCODES * HID];   // 9 KB
    int tid = threadIdx.x;
    for (int c = tid; c < NCODES * 32; c += 256)
        *(h8_t*)(et + c * 8) = *(const h8_t*)(etab + c * 8);
    __syncthreads();

    int w = tid >> 6;
    int l32 = tid & 31;
    int half = (tid >> 5) & 1;
    int base = blockIdx.x * 32 + w * 8;
    const h8_t hz = {};

    for (int t = 0; t < 4; ++t) {
        int node = base + t * 2 + half;
        if (node >= N) continue;
        h8_t self = *(const h8_t*)(zh + (size_t)node * HID + l32 * 8);
        float acc[8];
#pragma unroll
        for (int j = 0; j < 8; ++j) acc[j] = (float)self[j];
        int s = row_start[node];
        int e = row_start[node + 1];
        int i = s;
        for (; i + 4 <= e; i += 4) {
            unsigned p0 = csr[i], p1 = csr[i + 1], p2 = csr[i + 2], p3 = csr[i + 3];
            h8_t z0 = *(const h8_t*)(zh + (size_t)(p0 & 0xFFFFF) * HID + l32 * 8);
            h8_t z1 = *(const h8_t*)(zh + (size_t)(p1 & 0xFFFFF) * HID + l32 * 8);
            h8_t z2 = *(const h8_t*)(zh + (size_t)(p2 & 0xFFFFF) * HID + l32 * 8);
            h8_t z3 = *(const h8_t*)(zh + (size_t)(p3 & 0xFFFFF) * HID + l32 * 8);
            h8_t e0 = *(const h8_t*)(et + (p0 >> 20) * HID + l32 * 8);
            h8_t e1 = *(const h8_t*)(et + (p1 >> 20) * HID + l32 * 8);
            h8_t e2 = *(const h8_t*)(et + (p2 >> 20) * HID + l32 * 8);
            h8_t e3 = *(const h8_t*)(et + (p3 >> 20) * HID + l32 * 8);
            h8_t m0 = __builtin_elementwise_max(z0 + e0, hz);
            h8_t m1 = __builtin_elementwise_max(z1 + e1, hz);
            h8_t m2 = __builtin_elementwise_max(z2 + e2, hz);
            h8_t m3 = __builtin_elementwise_max(z3 + e3, hz);
            h8_t sm = (m0 + m1) + (m2 + m3);   // fp16 pairwise partial sum
#pragma unroll
            for (int j = 0; j < 8; ++j) acc[j] += (float)sm[j];
        }
        for (; i < e; ++i) {
            unsigned p0 = csr[i];
            h8_t z0 = *(const h8_t*)(zh + (size_t)(p0 & 0xFFFFF) * HID + l32 * 8);
            h8_t e0 = *(const h8_t*)(et + (p0 >> 20) * HID + l32 * 8);
            h8_t m0 = __builtin_elementwise_max(z0 + e0, hz);
#pragma unroll
            for (int j = 0; j < 8; ++j) acc[j] += (float)m0[j];
        }
        h8_t o;
#pragma unroll
        for (int j = 0; j < 8; ++j) o[j] = (_Float16)acc[j];
        *(h8_t*)(h0h + (size_t)node * HID + l32 * 8) = o;
    }
}

// MLP: z = relu( relu(A@W1+b1) @ W2 + b2 ).  512 thr / 8 waves; BM=64;
// wave w owns rows (w>>2)*32..+32, cols (w&3)*64..+64. 67.6 KB LDS -> 2 blocks/CU.
__global__ __launch_bounds__(512, 4) void mlp_kernel(const _Float16* __restrict__ A,
                                                     const _Float16* __restrict__ Wt1,
                                                     const float* __restrict__ b1,
                                                     const _Float16* __restrict__ Wt2,
                                                     const float* __restrict__ b2,
                                                     _Float16* __restrict__ outh,
                                                     float* __restrict__ outf,
                                                     int M, int writef) {
    __shared__ _Float16 As[64 * LROW];   // ~33.8 KB
    __shared__ _Float16 Ys[64 * LROW];   // ~33.8 KB
    int tid = threadIdx.x;
    int lane = tid & 63;
    int w = tid >> 6;
    int row0 = blockIdx.x * 64;
    const _Float16* Ab = A + (size_t)row0 * HID;

#pragma unroll
    for (int it = 0; it < 4; ++it) {
        int c = it * 512 + tid;
        int row = c >> 5, cir = c & 31;
        *(h8_t*)(As + row * LROW + cir * 8) = *(const h8_t*)(Ab + row * HID + cir * 8);
    }
    __syncthreads();

    int mh = (w >> 2) * 32;
    int wc = (w & 3) * 64;
    int l16 = lane & 15;
    int lq = lane >> 4;

    // ---- GEMM1: y = relu(A@W1+b1) -> Ys ----
    {
        f4_t acc[2][4] = {};
#pragma unroll
        for (int ks = 0; ks < 8; ++ks) {
            h8_t a[2], b[4];
#pragma unroll
            for (int mi = 0; mi < 2; ++mi)
                a[mi] = *(const h8_t*)(As + (mh + mi * 16 + l16) * LROW + (ks * 4 + lq) * 8);
#pragma unroll
            for (int ni = 0; ni < 4; ++ni)
                b[ni] = *(const h8_t*)(Wt1 + (size_t)(wc + ni * 16 + l16) * HID + ks * 32 + lq * 8);
#pragma unroll
            for (int mi = 0; mi < 2; ++mi)
#pragma unroll
                for (int ni = 0; ni < 4; ++ni)
                    acc[mi][ni] = __builtin_amdgcn_mfma_f32_16x16x32_f16(a[mi], b[ni], acc[mi][ni], 0, 0, 0);
        }
#pragma unroll
        for (int ni = 0; ni < 4; ++ni) {
            int col = wc + ni * 16 + l16;
            float bv = b1[col];
#pragma unroll
            for (int mi = 0; mi < 2; ++mi)
#pragma unroll
                for (int r = 0; r < 4; ++r) {
                    int rr = mh + mi * 16 + lq * 4 + r;
                    Ys[rr * LROW + col] = (_Float16)fmaxf(acc[mi][ni][r] + bv, 0.f);
                }
        }
    }
    __syncthreads();

    // ---- GEMM2: z = relu(y@W2+b2) -> As (reuse) ----
    {
        f4_t acc[2][4] = {};
#pragma unroll
        for (int ks = 0; ks < 8; ++ks) {
            h8_t a[2], b[4];
#pragma unroll
            for (int mi = 0; mi < 2; ++mi)
                a[mi] = *(const h8_t*)(Ys + (mh + mi * 16 + l16) * LROW + (ks * 4 + lq) * 8);
#pragma unroll
            for (int ni = 0; ni < 4; ++ni)
                b[ni] = *(const h8_t*)(Wt2 + (size_t)(wc + ni * 16 + l16) * HID + ks * 32 + lq * 8);
#pragma unroll
            for (int mi = 0; mi < 2; ++mi)
#pragma unroll
                for (int ni = 0; ni < 4; ++ni)
                    acc[mi][ni] = __builtin_amdgcn_mfma_f32_16x16x32_f16(a[mi], b[ni], acc[mi][ni], 0, 0, 0);
        }
        __syncthreads();
#pragma unroll
        for (int ni = 0; ni < 4; ++ni) {
            int col = wc + ni * 16 + l16;
            float bv = b2[col];
#pragma unroll
            for (int mi = 0; mi < 2; ++mi)
#pragma unroll
                for (int r = 0; r < 4; ++r) {
                    int rr = mh + mi * 16 + lq * 4 + r;
                    As[rr * LROW + col] = (_Float16)fmaxf(acc[mi][ni][r] + bv, 0.f);
                }
        }
    }
    __syncthreads();

    // ---- coalesced store ----
#pragma unroll
    for (int it = 0; it < 4; ++it) {
        int c = it * 512 + tid;
        int row = c >> 5, cir = c & 31;
        int grow = row0 + row;
        if (grow < M) {
            h8_t v = *(const h8_t*)(As + row * LROW + cir * 8);
            *(h8_t*)(outh + (size_t)grow * HID + cir * 8) = v;
            if (writef) {
                f4_t f0, f1;
#pragma unroll
                for (int j = 0; j < 4; ++j) { f0[j] = (float)v[j]; f1[j] = (float)v[j + 4]; }
                *(f4_t*)(outf + (size_t)grow * HID + cir * 8) = f0;
                *(f4_t*)(outf + (size_t)grow * HID + cir * 8 + 4) = f1;
            }
        }
    }
}

// mean pool from zh: 1024 thr/block, 32 rows in flight x 32 h8 chunks, LDS reduce
__global__ __launch_bounds__(1024) void pool_kernel(const _Float16* __restrict__ zh,
                                                    const int* __restrict__ batch, int N,
                                                    float* __restrict__ g) {
    __shared__ float red[32 * 32 * 8];
    int gid = blockIdx.x;
    int lo = 0, hi = N;
    while (lo < hi) { int mid = (lo + hi) >> 1; if (batch[mid] < gid) lo = mid + 1; else hi = mid; }
    int start = lo;
    int lo2 = start, hi2 = N;
    while (lo2 < hi2) { int mid = (lo2 + hi2) >> 1; if (batch[mid] < gid + 1) lo2 = mid + 1; else hi2 = mid; }
    int end = lo2;
    int cnt = end - start;

    int r = threadIdx.x >> 5;
    int ch = threadIdx.x & 31;
    float acc[8] = {};
    for (int row = start + r; row < end; row += 32) {
        h8_t v = *(const h8_t*)(zh + (size_t)row * HID + ch * 8);
#pragma unroll
        for (int j = 0; j < 8; ++j) acc[j] += (float)v[j];
    }
    float* slot = red + (r * 32 + ch) * 8;
#pragma unroll
    for (int j = 0; j < 8; ++j) slot[j] = acc[j];
    __syncthreads();
    for (int off = 16; off > 0; off >>= 1) {
        if (r < off) {
            const float* o = red + ((r + off) * 32 + ch) * 8;
#pragma unroll
            for (int j = 0; j < 8; ++j) { acc[j] += o[j]; slot[j] = acc[j]; }
        }
        __syncthreads();
    }
    if (r == 0) {
        float inv = 1.0f / fmaxf((float)cnt, 1.0f);
#pragma unroll
        for (int j = 0; j < 8; ++j) g[(size_t)gid * HID + ch * 8 + j] = acc[j] * inv;
    }
}

extern "C" void kernel_launch(void* const* d_in, const int* in_sizes, int n_in,
                              void* d_out, int out_size, void* d_ws, size_t ws_size,
                              hipStream_t stream) {
    const int* x = (const int*)d_in[0];
    const int* ei = (const int*)d_in[1];
    const int* ea = (const int*)d_in[2];
    const int* batch = (const int*)d_in[3];
    const float* xe1 = (const float*)d_in[4];
    const float* xe2 = (const float*)d_in[5];
    const float* ee1 = (const float*)d_in[6];
    const float* ee2 = (const float*)d_in[7];
    const float* W1 = (const float*)d_in[8];
    const float* b1 = (const float*)d_in[9];
    const float* W2 = (const float*)d_in[10];
    const float* b2 = (const float*)d_in[11];

    int N = in_sizes[0] / 2;
    int E = in_sizes[1] / 2;
    int G = out_size / HID - N;
    int nbm = (N + 63) / 64;
    int Np = nbm * 64;

    float* z = (float*)d_out;                       // [N,256] fp32 (final layer)
    float* gout = z + (size_t)N * HID;              // [G,256]

    char* w = (char*)d_ws;
    _Float16* h0h = (_Float16*)w;  w += (size_t)Np * HID * 2;
    _Float16* zh  = (_Float16*)w;  w += (size_t)Np * HID * 2;
    _Float16* Wt1 = (_Float16*)w;  w += (size_t)5 * HID * HID * 2;
    _Float16* Wt2 = (_Float16*)w;  w += (size_t)5 * HID * HID * 2;
    _Float16* etabh = (_Float16*)w; w += (size_t)NCODES * HID * 2;
    int* deg = (int*)w;       w += (size_t)N * 4;
    int* row_start = (int*)w; w += (size_t)(N + 1) * 4;
    int* cursor = (int*)w;    w += (size_t)N * 4;
    int* psum = (int*)w;      w += 64 * 4;
    unsigned* csr = (unsigned*)w;

    hipMemsetAsync(deg, 0, (size_t)N * 4, stream);
    etab_kernel<<<NCODES, HID, 0, stream>>>(ee1, ee2, etabh);
    embed_kernel<<<(N + 3) / 4, 256, 0, stream>>>(x, xe1, xe2, zh, N);
    prep_w<<<dim3(8, 8, 5), 256, 0, stream>>>(W1, Wt1);
    prep_w<<<dim3(8, 8, 5), 256, 0, stream>>>(W2, Wt2);
    hist_kernel<<<(E + 255) / 256, 256, 0, stream>>>(ei, E, deg);
    int nchunks = (N + SCAN_CHUNK - 1) / SCAN_CHUNK;
    scan_partial<<<nchunks, 256, 0, stream>>>(deg, N, psum);
    scan_sums<<<1, 1, 0, stream>>>(psum, nchunks);
    scan_apply<<<nchunks, 256, 0, stream>>>(deg, N, psum, row_start, cursor, E);
    fill_kernel<<<(E + 255) / 256, 256, 0, stream>>>(ei, ea, E, cursor, csr);

    for (int l = 0; l < 5; l++) {
        agg_kernel<<<(N + 31) / 32, 256, 0, stream>>>(zh, row_start, csr, etabh, h0h, N);
        mlp_kernel<<<nbm, 512, 0, stream>>>(h0h, Wt1 + (size_t)l * HID * HID,
                                            b1 + (size_t)l * HID,
                                            Wt2 + (size_t)l * HID * HID,
                                            b2 + (size_t)l * HID,
                                            zh, z, N, (l == 4) ? 1 : 0);
    }
    pool_kernel<<<G, 1024, 0, stream>>>(zh, batch, N, gout);
}